// Round 4
// baseline (138.631 us; speedup 1.0000x reference)
//
#include <hip/hip_runtime.h>
#include <math.h>

namespace {

constexpr int kB = 16, kL = 60, kNC = 80, kNA = 3, kNH = 76, kNW = 76, kNCH = 85;
constexpr int kPlane = kNH * kNW;              // 5776
constexpr int kCellsPerB = kNA * kPlane;       // 17328
constexpr int kBX = (kCellsPerB + 255) / 256;  // 68
constexpr int kNPart = kB * kBX;               // 1088
constexpr float kEps = 1e-16f;

// Static partial-sum buffer: avoids any dependence on ws_size (fully rewritten
// by main_loss on every call before finalize reads it -> no cross-call state).
__device__ float g_partials[kNPart];

// st row layout (12 floats = 48 B, 16B-aligned rows):
// [0..3] x1,y1,x2,y2  [4] area  [5] key(bits)  [6] dx [7] dy [8] lw [9] lh [10] sc [11] cls(bits)
__device__ __forceinline__ float sigm(float x) { return 1.0f / (1.0f + expf(-x)); }
// BCE(sigmoid(x), t) = softplus(x) - t*x ; stable softplus:
__device__ __forceinline__ float softplus(float x) {
  return fmaxf(x, 0.0f) + log1pf(expf(-fabsf(x)));
}
__device__ __forceinline__ float anchW(int a) { return a == 0 ? 1.25f : (a == 1 ? 2.0f : 4.125f); }
__device__ __forceinline__ float anchH(int a) { return a == 0 ? 1.625f : (a == 1 ? 3.75f : 2.875f); }

// ---------------- main: per-cell loss, label prep fused (grid = (68, B) x 256) ------------
// Only channels 0..4 are read in bulk; class channels only at the <=960 winner cells,
// drained wave-cooperatively (64 lanes per winner cell, not 80 serial loads per thread).
__global__ __launch_bounds__(256) void main_loss(const float* __restrict__ out,
                                                 const float* __restrict__ labels) {
  const int b = blockIdx.y;
  const int tid = threadIdx.x;
  __shared__ float st[kL][12];
  __shared__ int snv;

  if (tid < 64) {  // wave 0: per-label prep (labels are 19 KB total -> L2-resident)
    const int l = tid;
    const bool in = l < kL;
    float c0 = 0.f, x = 0.f, y = 0.f, w = 0.f, h = 0.f;
    if (in) {
      const float* p = labels + ((size_t)b * kL + l) * 5;
      c0 = p[0]; x = p[1]; y = p[2]; w = p[3]; h = p[4];
    }
    // n_valid = count of rows with sum>0 ; valid = l < n_valid (prefix, mirrors ref quirk)
    const unsigned long long m = __ballot(in && (c0 + x + y + w + h > 0.0f));
    const int nv = __popcll(m);
    if (l == 0) snv = nv;
    if (in) {
      const bool valid = l < nv;
      const float tx = x * (float)kNW, ty = y * (float)kNH;
      const float tw = w * (float)kNW, th = h * (float)kNH;
      const int ti = (int)tx, tj = (int)ty;

      // CIoU of [0,0,tw,th] vs [0,0,aw,ah] (xyxy path of pairwise_iou), first-max argmax
      const float at0 = atanf(tw / fmaxf(th, kEps));
      float best = -INFINITY;
      int bn = 0;
#pragma unroll
      for (int k = 0; k < kNA; ++k) {
        const float aw = anchW(k), ah = anchH(k);
        const float miw = fminf(tw, aw), mih = fminf(th, ah);
        const float en = ((0.0f < miw) && (0.0f < mih)) ? 1.0f : 0.0f;
        const float ai = miw * mih * en;
        const float au = tw * th + aw * ah - ai;
        const float iou = ai / fmaxf(au, kEps);
        const float dw = tw - aw, dh = th - ah;
        const float rho2 = (dw * dw + dh * dh) * 0.25f;
        const float mw = fmaxf(tw, aw), mh = fmaxf(th, ah);
        const float c2 = mw * mw + mh * mh + kEps;
        const float da = at0 - atanf(aw / ah);
        const float v = (4.0f / (float)(M_PI * M_PI)) * da * da;
        const float alpha = v / fmaxf(1.0f - iou + v, kEps);
        const float ciou = iou - (rho2 / c2 + v * alpha);
        if (ciou > best) { best = ciou; bn = k; }
      }
      st[l][0] = tx - tw * 0.5f; st[l][1] = ty - th * 0.5f;
      st[l][2] = tx + tw * 0.5f; st[l][3] = ty + th * 0.5f;
      st[l][4] = tw * th;
      st[l][5] = __int_as_float(valid ? ((bn * kNH + tj) * kNW + ti) : -1);
      st[l][6] = tx - floorf(tx);
      st[l][7] = ty - floorf(ty);
      st[l][8] = logf(tw / anchW(bn) + kEps);
      st[l][9] = logf(th / anchH(bn) + kEps);
      st[l][10] = sqrtf(2.0f - tw * th * (1.0f / (float)(kNW * kNH)));
      st[l][11] = __int_as_float((int)c0);
    }
  }
  __syncthreads();

  float acc = 0.0f;
  const int c = blockIdx.x * 256 + tid;
  int winner = -1;
  if (c < kCellsPerB) {
    const unsigned a = (unsigned)c / (unsigned)kPlane;
    const unsigned r = (unsigned)c - a * (unsigned)kPlane;
    const unsigned j = r / (unsigned)kNW;
    const unsigned i = r - j * (unsigned)kNW;
    const float* base = out + ((size_t)(b * kNA + (int)a) * kNCH) * kPlane + r;
    const float x0 = base[0];
    const float x1 = base[(size_t)kPlane];
    const float x2 = base[(size_t)2 * kPlane];
    const float x3 = base[(size_t)3 * kPlane];
    const float x4 = base[(size_t)4 * kPlane];

    // pred box (cx,cy,w,h) -> corners
    const float px = sigm(x0) + (float)i;
    const float py = sigm(x1) + (float)j;
    const float pw = expf(x2) * anchW((int)a);
    const float ph = expf(x3) * anchH((int)a);
    const float px1 = px - 0.5f * pw, px2 = px + 0.5f * pw;
    const float py1 = py - 0.5f * ph, py2 = py + 0.5f * ph;
    const float ap = pw * ph;

    // flag = (max IoU over valid targets) > 0.5 ; winner = last label scattering to this cell
    bool flag = false;
    const int nv = snv;
#pragma unroll 4
    for (int t = 0; t < nv; ++t) {
      const float4 bx = *reinterpret_cast<const float4*>(&st[t][0]);  // broadcast ds_read_b128
      const float2 ak = *reinterpret_cast<const float2*>(&st[t][4]);  // broadcast ds_read_b64
      const float tlx = fmaxf(px1, bx.x), tly = fmaxf(py1, bx.y);
      const float brx = fminf(px2, bx.z), bry = fminf(py2, bx.w);
      const bool ok = (tlx < brx) && (tly < bry);
      const float ai = ok ? (brx - tlx) * (bry - tly) : 0.0f;
      const float au = ap + ak.x - ai;        // au >= area_p >> eps always
      flag = flag || (ai + ai > au);          // iou > 0.5  (division-free, exact)
      if (__float_as_int(ak.y) == c) winner = t;  // last valid label wins collisions
    }

    const float sp4 = softplus(x4);
    if (winner >= 0) {
      // scattered cell: obj_mask=1, tobj=1, plus xy/wh terms (cls handled cooperatively below)
      acc += sp4 - x4;
      const float sc = st[winner][10];
      const float w2 = sc * sc;
      acc += (softplus(x0) - st[winner][6] * x0 + softplus(x1) - st[winner][7] * x1) * w2;
      const float d2 = x2 - st[winner][8], d3 = x3 - st[winner][9];
      acc += 0.5f * w2 * (d2 * d2 + d3 * d3);                               // loss_wh
    } else if (!flag) {
      acc += sp4;  // obj_mask=1 (best_iou<=0.5 or no valid targets), tobj=0
    }
    // else: obj_mask=0 -> contributes 0
  }

  // ---- wave-cooperative class loss for winner cells (<=960 total, ~0.2/wave) ----
  // 64 lanes load the 80 class logits of one winner cell in parallel (lane k -> classes
  // k and k+64), fusing the -x_cls term; ~1 memory round-trip per winner instead of 80.
  {
    const int lane = tid & 63;
    unsigned long long pend = __ballot(winner >= 0);
    while (pend) {
      const int src = (int)(__ffsll(pend) - 1);
      pend &= pend - 1;
      const int wc = __shfl(c, src);
      const int wt = __shfl(winner, src);
      const int cls = __float_as_int(st[wt][11]);  // same LDS addr across wave -> broadcast
      const unsigned wa = (unsigned)wc / (unsigned)kPlane;
      const unsigned wr = (unsigned)wc - wa * (unsigned)kPlane;
      const float* wb = out + ((size_t)(b * kNA + (int)wa) * kNCH + 5) * kPlane + wr;
      const float v0 = wb[(size_t)lane * kPlane];
      float s = softplus(v0) - (lane == cls ? v0 : 0.0f);
      if (lane < kNC - 64) {  // 16 lanes cover classes 64..79
        const float v1 = wb[(size_t)(lane + 64) * kPlane];
        s += softplus(v1) - (lane + 64 == cls ? v1 : 0.0f);
      }
#pragma unroll
      for (int off = 32; off > 0; off >>= 1) s += __shfl_down(s, off);
      if (lane == 0) acc += s;
    }
  }

  // deterministic block reduction (wave shfl + LDS)
#pragma unroll
  for (int off = 32; off > 0; off >>= 1) acc += __shfl_down(acc, off);
  __shared__ float sred[4];
  if ((tid & 63) == 0) sred[tid >> 6] = acc;
  __syncthreads();
  if (tid == 0) g_partials[b * kBX + blockIdx.x] = sred[0] + sred[1] + sred[2] + sred[3];
}

// ---------------- final deterministic reduce ----------------
__global__ void finalize(float* __restrict__ outp) {
  const int tid = threadIdx.x;
  double acc = 0.0;
  for (int idx = tid; idx < kNPart; idx += 256) acc += (double)g_partials[idx];
  __shared__ double s[256];
  s[tid] = acc;
  __syncthreads();
  for (int off = 128; off > 0; off >>= 1) {
    if (tid < off) s[tid] += s[tid + off];
    __syncthreads();
  }
  if (tid == 0) outp[0] = (float)(s[0] / (double)kB);
}

}  // namespace

extern "C" void kernel_launch(void* const* d_in, const int* in_sizes, int n_in,
                              void* d_out, int out_size, void* d_ws, size_t ws_size,
                              hipStream_t stream) {
  const float* output = (const float*)d_in[0];  // (B, NA*85, 76, 76) f32
  const float* target = (const float*)d_in[1];  // (B, L, 5) f32
  float* outp = (float*)d_out;                  // scalar f32
  (void)d_ws; (void)ws_size;                    // workspace unused (static g_partials)

  main_loss<<<dim3(kBX, kB), 256, 0, stream>>>(output, target);
  finalize<<<1, 256, 0, stream>>>(outp);
}